// Round 16
// baseline (347.311 us; speedup 1.0000x reference)
//
#include <hip/hip_runtime.h>

#define N_NODES 50000
#define N_EDGES 600000
#define DIM 128
#define N_GRAPHS 512
#define N_LAYERS 3
#define OUT_STRIDE (N_LAYERS * DIM)
#define BN_EPS 1e-5f
#define N_REP 16    // stats replicas (atomic decontention)
#define CAP 64      // bucket capacity per node (Poisson(12) max-degree << 64)

typedef __attribute__((ext_vector_type(8))) short short8;
typedef __attribute__((ext_vector_type(4))) float floatx4;

__device__ inline short f2bf(float f) {
    union { float f; unsigned u; } x{f};
    unsigned r = x.u + 0x7fffu + ((x.u >> 16) & 1u);
    return (short)(r >> 16);
}
__device__ inline float bf2f(short h) {
    union { unsigned u; float f; } x;
    x.u = ((unsigned)(unsigned short)h) << 16;
    return x.f;
}
// exact truncation split: f == bf2f(hi) + bf2f(lo) + O(2^-16 |f|)
__device__ inline void split_trunc(float f, short& hi, short& lo) {
    union { float f; unsigned u; } x{f};
    hi = (short)(x.u >> 16);
    union { unsigned u; float f; } hf;
    hf.u = x.u & 0xffff0000u;
    union { float f; unsigned u; } y{f - hf.f};
    lo = (short)(y.u >> 16);
}
// unpack 4 bf16 (packed little-endian in uint2) -> 4 fp32
__device__ inline floatx4 bf4_to_f4(uint2 w) {
    union { unsigned u; float f; } a, b, c, d;
    a.u = w.x << 16;
    b.u = w.x & 0xffff0000u;
    c.u = w.y << 16;
    d.u = w.y & 0xffff0000u;
    return floatx4{a.f, b.f, c.f, d.f};
}

// ------- prep: bucket-CSR (ushort) + per-graph count + weight split-convert + x->bf16 -------
__global__ __launch_bounds__(256) void prep_kernel(const int* __restrict__ src,
                                                   const int* __restrict__ dst,
                                                   const int* __restrict__ batch,
                                                   int* __restrict__ deg, int* __restrict__ cnt,
                                                   unsigned short* __restrict__ esrc,
                                                   const float* __restrict__ W1s,
                                                   const float* __restrict__ W2s,
                                                   short* __restrict__ Whi,
                                                   short* __restrict__ Wlo,
                                                   const float* __restrict__ x,
                                                   short* __restrict__ xb) {
    int i = blockIdx.x * 256 + threadIdx.x;
    if (i < N_EDGES) {
        int d = dst[i];
        int slot = atomicAdd(&deg[d], 1);
        if (slot < CAP) esrc[(d << 6) + slot] = (unsigned short)src[i];
    }
    if (i < N_NODES) atomicAdd(&cnt[batch[i]], 1);
    if (i < 6 * DIM * DIM) {
        int mat = i >> 14;
        int e = i & 16383;
        int k = e >> 7, n = e & 127;
        const float* W = (mat < 3) ? (W1s + (size_t)mat * DIM * DIM)
                                   : (W2s + (size_t)(mat - 3) * DIM * DIM);
        float w = W[e];
        short hi = f2bf(w);
        short lo = f2bf(w - bf2f(hi));
        size_t o = ((size_t)mat << 14) + n * DIM + k;
        Whi[o] = hi;
        Wlo[o] = lo;
    }
    if (i < N_NODES * 32) {
        float4 v = ((const float4*)x)[i];
        unsigned lo = (unsigned short)f2bf(v.x) | ((unsigned)(unsigned short)f2bf(v.y) << 16);
        unsigned hi = (unsigned short)f2bf(v.z) | ((unsigned)(unsigned short)f2bf(v.w) << 16);
        ((uint2*)xb)[i] = make_uint2(lo, hi);
    }
}

// ======== fused layer: BN-prep -> gather(bf16) -> GEMM1 -> GEMM2 -> stats+pool ========
// (R12/R14 hot structure — 61 us, 0 LDS conflicts — + in-kernel BN prep, ushort buckets.)
__global__ __launch_bounds__(256, 6) void fused_layer_kernel(
    const short* __restrict__ hin,      // prev raw h2 (or x), bf16 [N,128]
    const int* __restrict__ deg,
    const unsigned short* __restrict__ esrc,  // buckets [N][CAP] ushort
    const float* __restrict__ prevrep,  // prev layer stats replicas [N_REP][256] or null
    const float* __restrict__ pgamma,
    const float* __restrict__ pbeta,
    const short* __restrict__ W1hi, const short* __restrict__ W1lo,
    const float* __restrict__ b1,
    const short* __restrict__ W2hi, const short* __restrict__ W2lo,
    const float* __restrict__ b2,
    const int* __restrict__ batch,
    short* __restrict__ out,        // raw h2 bf16 [N,128]
    float* __restrict__ srep,       // this layer's stats replicas [N_REP][256]
    float* __restrict__ gout,       // [G, 384]
    int layer) {
    __shared__ unsigned sbuf[4096];  // 16 KB, aliased across phases
    __shared__ float GO_s[256];      // G[128] | OFF[128]
    short* As_hi = (short*)sbuf;           // [32][128] shorts, chunk^row swizzle (8 KB)
    short* As_lo = (short*)(sbuf + 2048);  // (8 KB)
    const int tid = threadIdx.x;
    const int base = blockIdx.x * 32;

    // ---- phase P: reduce prev replicas -> G/OFF (L2-hot, 4 KB/block) ----
    if (prevrep) {
        float s = 0.f;
#pragma unroll
        for (int r = 0; r < N_REP; ++r) s += prevrep[r * 256 + tid];
        GO_s[tid] = s;
        __syncthreads();
        if (tid < 128) {
            const float invn = 1.0f / (float)N_NODES;
            float m = GO_s[tid] * invn;
            float var = GO_s[128 + tid] * invn - m * m;
            float G = pgamma[tid] * rsqrtf(var + BN_EPS);
            GO_s[tid] = G;  // same-thread read->write
            GO_s[128 + tid] = pbeta[tid] - m * G;
        }
    } else {
        GO_s[tid] = (tid < 128) ? 1.f : 0.f;
    }
    __syncthreads();

    // ---- phase G: gather (bf16, half-wave uint2 lanes; uint4 index loads) ----
    {
        const int hw = tid >> 5;   // half-wave 0..7
        const int l32 = tid & 31;  // owns cols [4*l32, 4*l32+4)
        floatx4 G4 = *(const floatx4*)&GO_s[4 * l32];
        floatx4 O4 = *(const floatx4*)&GO_s[128 + 4 * l32];
        const uint2* hb = (const uint2*)hin;  // row stride 32 uint2 (128 bf16)
#pragma unroll
        for (int i = 0; i < 4; ++i) {
            int r = hw * 4 + i;
            int node = base + r;
            floatx4 acc = {0.f, 0.f, 0.f, 0.f};
            if (node < N_NODES) {
                acc = bf4_to_f4(hb[(size_t)node * 32 + l32]);  // self (eps=0)
                int dgr = deg[node];
                if (dgr > CAP) dgr = CAP;
                const unsigned short* eb = esrc + ((size_t)node << 6);  // 16B-aligned bucket
                int j = 0;
                for (; j + 8 <= dgr; j += 8) {
                    uint4 iw = *(const uint4*)(eb + j);  // 8 indices in one load
                    int s0 = iw.x & 0xffff, s1 = iw.x >> 16;
                    int s2 = iw.y & 0xffff, s3 = iw.y >> 16;
                    int s4 = iw.z & 0xffff, s5 = iw.z >> 16;
                    int s6 = iw.w & 0xffff, s7 = iw.w >> 16;
                    uint2 w0 = hb[(size_t)s0 * 32 + l32];
                    uint2 w1 = hb[(size_t)s1 * 32 + l32];
                    uint2 w2 = hb[(size_t)s2 * 32 + l32];
                    uint2 w3 = hb[(size_t)s3 * 32 + l32];
                    uint2 w4 = hb[(size_t)s4 * 32 + l32];
                    uint2 w5 = hb[(size_t)s5 * 32 + l32];
                    uint2 w6 = hb[(size_t)s6 * 32 + l32];
                    uint2 w7 = hb[(size_t)s7 * 32 + l32];
                    acc += ((bf4_to_f4(w0) + bf4_to_f4(w1)) + (bf4_to_f4(w2) + bf4_to_f4(w3))) +
                           ((bf4_to_f4(w4) + bf4_to_f4(w5)) + (bf4_to_f4(w6) + bf4_to_f4(w7)));
                }
                if (j + 4 <= dgr) {
                    uint2 iw = *(const uint2*)(eb + j);  // 4 indices
                    int s0 = iw.x & 0xffff, s1 = iw.x >> 16;
                    int s2 = iw.y & 0xffff, s3 = iw.y >> 16;
                    uint2 w0 = hb[(size_t)s0 * 32 + l32];
                    uint2 w1 = hb[(size_t)s1 * 32 + l32];
                    uint2 w2 = hb[(size_t)s2 * 32 + l32];
                    uint2 w3 = hb[(size_t)s3 * 32 + l32];
                    acc += (bf4_to_f4(w0) + bf4_to_f4(w1)) + (bf4_to_f4(w2) + bf4_to_f4(w3));
                    j += 4;
                }
                for (; j < dgr; ++j) acc += bf4_to_f4(hb[(size_t)eb[j] * 32 + l32]);
                float dp1 = (float)(dgr + 1);
                acc = G4 * acc + dp1 * O4;
            }
            short hi[4], lo[4];
#pragma unroll
            for (int q = 0; q < 4; ++q) split_trunc(acc[q], hi[q], lo[q]);
            unsigned h0 = (unsigned short)hi[0] | ((unsigned)(unsigned short)hi[1] << 16);
            unsigned h1 = (unsigned short)hi[2] | ((unsigned)(unsigned short)hi[3] << 16);
            unsigned l0 = (unsigned short)lo[0] | ((unsigned)(unsigned short)lo[1] << 16);
            unsigned l1 = (unsigned short)lo[2] | ((unsigned)(unsigned short)lo[3] << 16);
            int ch = l32 >> 1, half = l32 & 1;
            int pos = r * 128 + ((ch ^ (r & 15)) * 8) + half * 4;
            *(uint2*)&As_hi[pos] = make_uint2(h0, h1);
            *(uint2*)&As_lo[pos] = make_uint2(l0, l1);
        }
    }
    __syncthreads();

    const int wave = tid >> 6;
    const int lane = tid & 63;
    const int l15 = lane & 15;
    const int quad = lane >> 4;
    // wave owns cols [wave*32, wave*32+32): ni tiles {wave*2, wave*2+1}

    // ---- phase 1: GEMM1 (A from LDS, W fragments from global; each ni read by one wave) ----
    floatx4 acc[2][2];
#pragma unroll
    for (int mi = 0; mi < 2; ++mi)
#pragma unroll
        for (int nl = 0; nl < 2; ++nl) acc[mi][nl] = floatx4{0.f, 0.f, 0.f, 0.f};
#pragma unroll
    for (int ks = 0; ks < 4; ++ks) {
        short8 ahi[2], alo[2], bhi[2], blo[2];
#pragma unroll
        for (int mi = 0; mi < 2; ++mi) {
            int row = mi * 16 + l15;
            int pos = row * 128 + (((ks * 4 + quad) ^ l15) * 8);
            ahi[mi] = *(const short8*)&As_hi[pos];
            alo[mi] = *(const short8*)&As_lo[pos];
        }
#pragma unroll
        for (int nl = 0; nl < 2; ++nl) {
            size_t p = (size_t)((wave * 2 + nl) * 16 + l15) * DIM + ks * 32 + quad * 8;
            bhi[nl] = *(const short8*)&W1hi[p];
            blo[nl] = *(const short8*)&W1lo[p];
        }
#pragma unroll
        for (int mi = 0; mi < 2; ++mi)
#pragma unroll
            for (int nl = 0; nl < 2; ++nl) {
                acc[mi][nl] = __builtin_amdgcn_mfma_f32_16x16x32_bf16(ahi[mi], bhi[nl], acc[mi][nl], 0, 0, 0);
                acc[mi][nl] = __builtin_amdgcn_mfma_f32_16x16x32_bf16(alo[mi], bhi[nl], acc[mi][nl], 0, 0, 0);
                acc[mi][nl] = __builtin_amdgcn_mfma_f32_16x16x32_bf16(ahi[mi], blo[nl], acc[mi][nl], 0, 0, 0);
            }
    }
    __syncthreads();  // all As reads complete before overwrite

    // ---- phase 2: bias1 + relu, trunc-split, pack (hi<<16|lo) -> LDS u32, 16B-chunk swizzle ----
#pragma unroll
    for (int mi = 0; mi < 2; ++mi)
#pragma unroll
        for (int nl = 0; nl < 2; ++nl) {
            int col = (wave * 2 + nl) * 16 + l15;
            float bv = b1[col];
#pragma unroll
            for (int reg = 0; reg < 4; ++reg) {
                int row = mi * 16 + quad * 4 + reg;
                float v = fmaxf(acc[mi][nl][reg] + bv, 0.f);
                union { float f; unsigned u; } x{v};
                union { unsigned u; float f; } hf;
                hf.u = x.u & 0xffff0000u;
                union { float f; unsigned u; } y{v - hf.f};
                unsigned w = hf.u | (y.u >> 16);
                sbuf[row * 128 + ((((col >> 2) ^ (row & 31)) * 4) + (col & 3))] = w;
            }
        }
    __syncthreads();

    // ---- phase 3: GEMM2 from packed h1 ----
    floatx4 acc2[2][2];
#pragma unroll
    for (int mi = 0; mi < 2; ++mi)
#pragma unroll
        for (int nl = 0; nl < 2; ++nl) acc2[mi][nl] = floatx4{0.f, 0.f, 0.f, 0.f};
#pragma unroll
    for (int ks = 0; ks < 4; ++ks) {
        short8 ahi2[2], alo2[2], bhi[2], blo[2];
#pragma unroll
        for (int mi = 0; mi < 2; ++mi) {
            int row = mi * 16 + l15;
            int c5 = ks * 8 + quad * 2;
            unsigned w[8];
            *(uint4*)&w[0] = *(const uint4*)&sbuf[row * 128 + ((c5 ^ (row & 31)) * 4)];
            *(uint4*)&w[4] = *(const uint4*)&sbuf[row * 128 + (((c5 + 1) ^ (row & 31)) * 4)];
#pragma unroll
            for (int j = 0; j < 8; ++j) {
                ahi2[mi][j] = (short)(w[j] >> 16);
                alo2[mi][j] = (short)(w[j] & 0xffffu);
            }
        }
#pragma unroll
        for (int nl = 0; nl < 2; ++nl) {
            size_t p = (size_t)((wave * 2 + nl) * 16 + l15) * DIM + ks * 32 + quad * 8;
            bhi[nl] = *(const short8*)&W2hi[p];
            blo[nl] = *(const short8*)&W2lo[p];
        }
#pragma unroll
        for (int mi = 0; mi < 2; ++mi)
#pragma unroll
            for (int nl = 0; nl < 2; ++nl) {
                acc2[mi][nl] = __builtin_amdgcn_mfma_f32_16x16x32_bf16(ahi2[mi], bhi[nl], acc2[mi][nl], 0, 0, 0);
                acc2[mi][nl] = __builtin_amdgcn_mfma_f32_16x16x32_bf16(alo2[mi], bhi[nl], acc2[mi][nl], 0, 0, 0);
                acc2[mi][nl] = __builtin_amdgcn_mfma_f32_16x16x32_bf16(ahi2[mi], blo[nl], acc2[mi][nl], 0, 0, 0);
            }
    }
    __syncthreads();  // phase-3 sbuf reads done; reuse LDS for pool/stats

    // ---- phase 4: epilogue — bf16 h2 store + stats + pool (unique-writer LDS) ----
    float* pool_s = (float*)sbuf;      // [3 slot][128 col]
    float* ssum = (float*)sbuf + 384;  // [128]
    float* ssq = (float*)sbuf + 512;   // [128]

    const int g0 = batch[base];
    int idxr[2][4];
#pragma unroll
    for (int mi = 0; mi < 2; ++mi)
#pragma unroll
        for (int reg = 0; reg < 4; ++reg) {
            int row = base + mi * 16 + quad * 4 + reg;
            idxr[mi][reg] = (row < N_NODES) ? (batch[row] - g0) : -1;
        }

#pragma unroll
    for (int nl = 0; nl < 2; ++nl) {
        int col = (wave * 2 + nl) * 16 + l15;
        float bv = b2[col];
        float s_p = 0.f, q_p = 0.f, p0 = 0.f, p1 = 0.f, p2 = 0.f;
#pragma unroll
        for (int mi = 0; mi < 2; ++mi)
#pragma unroll
            for (int reg = 0; reg < 4; ++reg) {
                int idx = idxr[mi][reg];
                if (idx >= 0) {
                    int row = base + mi * 16 + quad * 4 + reg;
                    float v = fmaxf(acc2[mi][nl][reg] + bv, 0.f);
                    out[(size_t)row * DIM + col] = f2bf(v);
                    s_p += v;
                    q_p += v * v;
                    if (idx == 0) p0 += v;
                    else if (idx == 1) p1 += v;
                    else if (idx == 2) p2 += v;
                    else atomicAdd(&gout[(size_t)(g0 + idx) * OUT_STRIDE + layer * DIM + col], v);
                }
            }
        s_p += __shfl_xor(s_p, 16);
        s_p += __shfl_xor(s_p, 32);
        q_p += __shfl_xor(q_p, 16);
        q_p += __shfl_xor(q_p, 32);
        p0 += __shfl_xor(p0, 16);
        p0 += __shfl_xor(p0, 32);
        p1 += __shfl_xor(p1, 16);
        p1 += __shfl_xor(p1, 32);
        p2 += __shfl_xor(p2, 16);
        p2 += __shfl_xor(p2, 32);
        if (quad == 0) {  // unique writer per col
            ssum[col] = s_p;
            ssq[col] = q_p;
            pool_s[col] = p0;
            pool_s[128 + col] = p1;
            pool_s[256 + col] = p2;
        }
    }
    __syncthreads();

    // stats -> replicated buffer (blockIdx&15): ~98-way contention instead of 1563-way
    float* srep_b = srep + (blockIdx.x & (N_REP - 1)) * 256;
    if (tid < 128)
        atomicAdd(&srep_b[tid], ssum[tid]);
    else
        atomicAdd(&srep_b[tid], ssq[tid - 128]);
    for (int i = tid; i < 384; i += 256) {
        int slot = i >> 7, col = i & 127;
        float pv = pool_s[slot * 128 + col];
        int g = g0 + slot;
        if (pv != 0.f && g < N_GRAPHS)
            atomicAdd(&gout[(size_t)g * OUT_STRIDE + layer * DIM + col], pv);
    }
}

// ------- finalize: reduce replicas, out[b, l*128+c] = G_l[c]*rawpool + cnt[b]*OFF_l[c] -------
__global__ __launch_bounds__(384) void finalize_kernel(const float* __restrict__ rep,
                                                       const float* __restrict__ gammas,
                                                       const float* __restrict__ betas,
                                                       const int* __restrict__ cnt,
                                                       float* __restrict__ out) {
    int b = blockIdx.x;
    int t = threadIdx.x;
    int l = t >> 7, c = t & 127;
    const float* rl = rep + (size_t)l * N_REP * 256;
    float s = 0.f, q = 0.f;
#pragma unroll
    for (int r = 0; r < N_REP; ++r) {
        s += rl[r * 256 + c];
        q += rl[r * 256 + 128 + c];
    }
    const float invn = 1.0f / (float)N_NODES;
    float m = s * invn;
    float var = q * invn - m * m;
    float G = gammas[l * DIM + c] * rsqrtf(var + BN_EPS);
    float OFF = betas[l * DIM + c] - m * G;
    size_t o = (size_t)b * OUT_STRIDE + t;
    out[o] = fmaf(G, out[o], (float)cnt[b] * OFF);
}

extern "C" void kernel_launch(void* const* d_in, const int* in_sizes, int n_in,
                              void* d_out, int out_size, void* d_ws, size_t ws_size,
                              hipStream_t stream) {
    const float* x = (const float*)d_in[0];
    const int* ei = (const int*)d_in[1];
    const int* srcp = ei;
    const int* dstp = ei + N_EDGES;
    const int* batch = (const int*)d_in[2];
    const float* W1s = (const float*)d_in[3];
    const float* b1s = (const float*)d_in[4];
    const float* W2s = (const float*)d_in[5];
    const float* b2s = (const float*)d_in[6];
    const float* gammas = (const float*)d_in[7];
    const float* betas = (const float*)d_in[8];
    float* out = (float*)d_out;

    const size_t NF = (size_t)N_NODES * DIM;  // 6.4M elements
    short* hbufA = (short*)d_ws;              // bf16 [N,128]
    short* hbufB = hbufA + NF;                // bf16 [N,128]
    short* xb = hbufB + NF;                   // bf16 [N,128] (x converted)
    short* whi = xb + NF;                     // bf16 hi [6][128][128]
    short* wlo = whi + 6 * DIM * DIM;         // bf16 lo [6][128][128]
    float* stats_rep = (float*)(wlo + 6 * DIM * DIM);  // [3][N_REP][256]
    int* cnt = (int*)(stats_rep + 3 * N_REP * 256);    // 512
    int* deg = cnt + N_GRAPHS;                // 50000
    unsigned short* esrc = (unsigned short*)(deg + N_NODES);  // buckets [N][CAP] ushort (6.4 MB)

    hipMemsetAsync(out, 0, (size_t)N_GRAPHS * OUT_STRIDE * sizeof(float), stream);
    // zero stats_rep + cnt + deg (contiguous)
    hipMemsetAsync(stats_rep, 0,
                   (3 * N_REP * 256) * sizeof(float) + (N_GRAPHS + N_NODES) * sizeof(int), stream);

    // one prep dispatch: bucket-CSR + counts + weight/x converts
    prep_kernel<<<(N_NODES * 32 + 255) / 256, 256, 0, stream>>>(srcp, dstp, batch, deg, cnt, esrc,
                                                                W1s, W2s, whi, wlo, x, xb);

    const int nblk = (N_NODES + 31) / 32;  // 1563
    const short* hin = xb;
    short* hout = hbufA;
    for (int layer = 0; layer < N_LAYERS; ++layer) {
        const float* prevrep =
            (layer == 0) ? nullptr : (stats_rep + (size_t)(layer - 1) * N_REP * 256);
        fused_layer_kernel<<<nblk, 256, 0, stream>>>(
            hin, deg, esrc, prevrep, gammas + (layer - 1) * DIM, betas + (layer - 1) * DIM,
            whi + ((size_t)layer << 14), wlo + ((size_t)layer << 14), b1s + layer * DIM,
            whi + ((size_t)(3 + layer) << 14), wlo + ((size_t)(3 + layer) << 14),
            b2s + layer * DIM, batch, hout, stats_rep + (size_t)layer * N_REP * 256, out, layer);
        hin = hout;
        hout = (hout == hbufA) ? hbufB : hbufA;
    }
    finalize_kernel<<<N_GRAPHS, 384, 0, stream>>>(stats_rep, gammas, betas, cnt, out);
}

// Round 17
// 314.517 us; speedup vs baseline: 1.1043x; 1.1043x over previous
//
#include <hip/hip_runtime.h>

#define N_NODES 50000
#define N_EDGES 600000
#define DIM 128
#define N_GRAPHS 512
#define N_LAYERS 3
#define OUT_STRIDE (N_LAYERS * DIM)
#define BN_EPS 1e-5f
#define N_REP 16    // stats replicas (atomic decontention)
#define CAP 64      // bucket capacity per node (Poisson(12) max-degree << 64)

typedef __attribute__((ext_vector_type(8))) short short8;
typedef __attribute__((ext_vector_type(4))) float floatx4;

__device__ inline short f2bf(float f) {
    union { float f; unsigned u; } x{f};
    unsigned r = x.u + 0x7fffu + ((x.u >> 16) & 1u);
    return (short)(r >> 16);
}
__device__ inline float bf2f(short h) {
    union { unsigned u; float f; } x;
    x.u = ((unsigned)(unsigned short)h) << 16;
    return x.f;
}
// exact truncation split: f == bf2f(hi) + bf2f(lo) + O(2^-16 |f|)
__device__ inline void split_trunc(float f, short& hi, short& lo) {
    union { float f; unsigned u; } x{f};
    hi = (short)(x.u >> 16);
    union { unsigned u; float f; } hf;
    hf.u = x.u & 0xffff0000u;
    union { float f; unsigned u; } y{f - hf.f};
    lo = (short)(y.u >> 16);
}
// unpack 4 bf16 (packed little-endian in uint2) -> 4 fp32
__device__ inline floatx4 bf4_to_f4(uint2 w) {
    union { unsigned u; float f; } a, b, c, d;
    a.u = w.x << 16;
    b.u = w.x & 0xffff0000u;
    c.u = w.y << 16;
    d.u = w.y & 0xffff0000u;
    return floatx4{a.f, b.f, c.f, d.f};
}

// ------- prep: bucket-CSR (ushort) + per-graph count + weight split-convert + x->bf16 -------
__global__ __launch_bounds__(256) void prep_kernel(const int* __restrict__ src,
                                                   const int* __restrict__ dst,
                                                   const int* __restrict__ batch,
                                                   int* __restrict__ deg, int* __restrict__ cnt,
                                                   unsigned short* __restrict__ esrc,
                                                   const float* __restrict__ W1s,
                                                   const float* __restrict__ W2s,
                                                   short* __restrict__ Whi,
                                                   short* __restrict__ Wlo,
                                                   const float* __restrict__ x,
                                                   short* __restrict__ xb) {
    int i = blockIdx.x * 256 + threadIdx.x;
    if (i < N_EDGES) {
        int d = dst[i];
        int slot = atomicAdd(&deg[d], 1);
        if (slot < CAP) esrc[(d << 6) + slot] = (unsigned short)src[i];
    }
    if (i < N_NODES) atomicAdd(&cnt[batch[i]], 1);
    if (i < 6 * DIM * DIM) {
        int mat = i >> 14;
        int e = i & 16383;
        int k = e >> 7, n = e & 127;
        const float* W = (mat < 3) ? (W1s + (size_t)mat * DIM * DIM)
                                   : (W2s + (size_t)(mat - 3) * DIM * DIM);
        float w = W[e];
        short hi = f2bf(w);
        short lo = f2bf(w - bf2f(hi));
        size_t o = ((size_t)mat << 14) + n * DIM + k;
        Whi[o] = hi;
        Wlo[o] = lo;
    }
    if (i < N_NODES * 32) {
        float4 v = ((const float4*)x)[i];
        unsigned lo = (unsigned short)f2bf(v.x) | ((unsigned)(unsigned short)f2bf(v.y) << 16);
        unsigned hi = (unsigned short)f2bf(v.z) | ((unsigned)(unsigned short)f2bf(v.w) << 16);
        ((uint2*)xb)[i] = make_uint2(lo, hi);
    }
}

// ======== fused layer: BN-prep -> gather(bf16) -> GEMM1 -> GEMM2 -> stats+pool ========
// (R12/R14 hot structure — 61 us, 0 LDS conflicts — + in-kernel BN prep, ushort buckets.
//  Index loads are 8 INDEPENDENT scalar ushort loads: fine-grained vmcnt interleave — the
//  R16 uint4 index load serialized the gather and cost 10 us.)
__global__ __launch_bounds__(256, 6) void fused_layer_kernel(
    const short* __restrict__ hin,      // prev raw h2 (or x), bf16 [N,128]
    const int* __restrict__ deg,
    const unsigned short* __restrict__ esrc,  // buckets [N][CAP] ushort
    const float* __restrict__ prevrep,  // prev layer stats replicas [N_REP][256] or null
    const float* __restrict__ pgamma,
    const float* __restrict__ pbeta,
    const short* __restrict__ W1hi, const short* __restrict__ W1lo,
    const float* __restrict__ b1,
    const short* __restrict__ W2hi, const short* __restrict__ W2lo,
    const float* __restrict__ b2,
    const int* __restrict__ batch,
    short* __restrict__ out,        // raw h2 bf16 [N,128]
    float* __restrict__ srep,       // this layer's stats replicas [N_REP][256]
    float* __restrict__ gout,       // [G, 384]
    int layer) {
    __shared__ unsigned sbuf[4096];  // 16 KB, aliased across phases
    __shared__ float GO_s[256];      // G[128] | OFF[128]
    short* As_hi = (short*)sbuf;           // [32][128] shorts, chunk^row swizzle (8 KB)
    short* As_lo = (short*)(sbuf + 2048);  // (8 KB)
    const int tid = threadIdx.x;
    const int base = blockIdx.x * 32;

    // ---- phase P: reduce prev replicas -> G/OFF (L2-hot, 4 KB/block) ----
    if (prevrep) {
        float s = 0.f;
#pragma unroll
        for (int r = 0; r < N_REP; ++r) s += prevrep[r * 256 + tid];
        GO_s[tid] = s;
        __syncthreads();
        if (tid < 128) {
            const float invn = 1.0f / (float)N_NODES;
            float m = GO_s[tid] * invn;
            float var = GO_s[128 + tid] * invn - m * m;
            float G = pgamma[tid] * rsqrtf(var + BN_EPS);
            GO_s[tid] = G;  // same-thread read->write
            GO_s[128 + tid] = pbeta[tid] - m * G;
        }
    } else {
        GO_s[tid] = (tid < 128) ? 1.f : 0.f;
    }
    __syncthreads();

    // ---- phase G: gather (bf16, half-wave uint2 lanes; independent scalar index loads) ----
    {
        const int hw = tid >> 5;   // half-wave 0..7
        const int l32 = tid & 31;  // owns cols [4*l32, 4*l32+4)
        floatx4 G4 = *(const floatx4*)&GO_s[4 * l32];
        floatx4 O4 = *(const floatx4*)&GO_s[128 + 4 * l32];
        const uint2* hb = (const uint2*)hin;  // row stride 32 uint2 (128 bf16)
#pragma unroll
        for (int i = 0; i < 4; ++i) {
            int r = hw * 4 + i;
            int node = base + r;
            floatx4 acc = {0.f, 0.f, 0.f, 0.f};
            if (node < N_NODES) {
                acc = bf4_to_f4(hb[(size_t)node * 32 + l32]);  // self (eps=0)
                int dgr = deg[node];
                if (dgr > CAP) dgr = CAP;
                const unsigned short* eb = esrc + ((size_t)node << 6);
                int j = 0;
                for (; j + 8 <= dgr; j += 8) {
                    int s0 = eb[j], s1 = eb[j + 1], s2 = eb[j + 2], s3 = eb[j + 3];
                    int s4 = eb[j + 4], s5 = eb[j + 5], s6 = eb[j + 6], s7 = eb[j + 7];
                    uint2 w0 = hb[(size_t)s0 * 32 + l32];
                    uint2 w1 = hb[(size_t)s1 * 32 + l32];
                    uint2 w2 = hb[(size_t)s2 * 32 + l32];
                    uint2 w3 = hb[(size_t)s3 * 32 + l32];
                    uint2 w4 = hb[(size_t)s4 * 32 + l32];
                    uint2 w5 = hb[(size_t)s5 * 32 + l32];
                    uint2 w6 = hb[(size_t)s6 * 32 + l32];
                    uint2 w7 = hb[(size_t)s7 * 32 + l32];
                    acc += ((bf4_to_f4(w0) + bf4_to_f4(w1)) + (bf4_to_f4(w2) + bf4_to_f4(w3))) +
                           ((bf4_to_f4(w4) + bf4_to_f4(w5)) + (bf4_to_f4(w6) + bf4_to_f4(w7)));
                }
                if (j + 4 <= dgr) {
                    int s0 = eb[j], s1 = eb[j + 1], s2 = eb[j + 2], s3 = eb[j + 3];
                    uint2 w0 = hb[(size_t)s0 * 32 + l32];
                    uint2 w1 = hb[(size_t)s1 * 32 + l32];
                    uint2 w2 = hb[(size_t)s2 * 32 + l32];
                    uint2 w3 = hb[(size_t)s3 * 32 + l32];
                    acc += (bf4_to_f4(w0) + bf4_to_f4(w1)) + (bf4_to_f4(w2) + bf4_to_f4(w3));
                    j += 4;
                }
                for (; j < dgr; ++j) acc += bf4_to_f4(hb[(size_t)eb[j] * 32 + l32]);
                float dp1 = (float)(dgr + 1);
                acc = G4 * acc + dp1 * O4;
            }
            short hi[4], lo[4];
#pragma unroll
            for (int q = 0; q < 4; ++q) split_trunc(acc[q], hi[q], lo[q]);
            unsigned h0 = (unsigned short)hi[0] | ((unsigned)(unsigned short)hi[1] << 16);
            unsigned h1 = (unsigned short)hi[2] | ((unsigned)(unsigned short)hi[3] << 16);
            unsigned l0 = (unsigned short)lo[0] | ((unsigned)(unsigned short)lo[1] << 16);
            unsigned l1 = (unsigned short)lo[2] | ((unsigned)(unsigned short)lo[3] << 16);
            int ch = l32 >> 1, half = l32 & 1;
            int pos = r * 128 + ((ch ^ (r & 15)) * 8) + half * 4;
            *(uint2*)&As_hi[pos] = make_uint2(h0, h1);
            *(uint2*)&As_lo[pos] = make_uint2(l0, l1);
        }
    }
    __syncthreads();

    const int wave = tid >> 6;
    const int lane = tid & 63;
    const int l15 = lane & 15;
    const int quad = lane >> 4;
    // wave owns cols [wave*32, wave*32+32): ni tiles {wave*2, wave*2+1}

    // ---- phase 1: GEMM1 (A from LDS, W fragments from global; each ni read by one wave) ----
    floatx4 acc[2][2];
#pragma unroll
    for (int mi = 0; mi < 2; ++mi)
#pragma unroll
        for (int nl = 0; nl < 2; ++nl) acc[mi][nl] = floatx4{0.f, 0.f, 0.f, 0.f};
#pragma unroll
    for (int ks = 0; ks < 4; ++ks) {
        short8 ahi[2], alo[2], bhi[2], blo[2];
#pragma unroll
        for (int mi = 0; mi < 2; ++mi) {
            int row = mi * 16 + l15;
            int pos = row * 128 + (((ks * 4 + quad) ^ l15) * 8);
            ahi[mi] = *(const short8*)&As_hi[pos];
            alo[mi] = *(const short8*)&As_lo[pos];
        }
#pragma unroll
        for (int nl = 0; nl < 2; ++nl) {
            size_t p = (size_t)((wave * 2 + nl) * 16 + l15) * DIM + ks * 32 + quad * 8;
            bhi[nl] = *(const short8*)&W1hi[p];
            blo[nl] = *(const short8*)&W1lo[p];
        }
#pragma unroll
        for (int mi = 0; mi < 2; ++mi)
#pragma unroll
            for (int nl = 0; nl < 2; ++nl) {
                acc[mi][nl] = __builtin_amdgcn_mfma_f32_16x16x32_bf16(ahi[mi], bhi[nl], acc[mi][nl], 0, 0, 0);
                acc[mi][nl] = __builtin_amdgcn_mfma_f32_16x16x32_bf16(alo[mi], bhi[nl], acc[mi][nl], 0, 0, 0);
                acc[mi][nl] = __builtin_amdgcn_mfma_f32_16x16x32_bf16(ahi[mi], blo[nl], acc[mi][nl], 0, 0, 0);
            }
    }
    __syncthreads();  // all As reads complete before overwrite

    // ---- phase 2: bias1 + relu, trunc-split, pack (hi<<16|lo) -> LDS u32, 16B-chunk swizzle ----
#pragma unroll
    for (int mi = 0; mi < 2; ++mi)
#pragma unroll
        for (int nl = 0; nl < 2; ++nl) {
            int col = (wave * 2 + nl) * 16 + l15;
            float bv = b1[col];
#pragma unroll
            for (int reg = 0; reg < 4; ++reg) {
                int row = mi * 16 + quad * 4 + reg;
                float v = fmaxf(acc[mi][nl][reg] + bv, 0.f);
                union { float f; unsigned u; } x{v};
                union { unsigned u; float f; } hf;
                hf.u = x.u & 0xffff0000u;
                union { float f; unsigned u; } y{v - hf.f};
                unsigned w = hf.u | (y.u >> 16);
                sbuf[row * 128 + ((((col >> 2) ^ (row & 31)) * 4) + (col & 3))] = w;
            }
        }
    __syncthreads();

    // ---- phase 3: GEMM2 from packed h1 ----
    floatx4 acc2[2][2];
#pragma unroll
    for (int mi = 0; mi < 2; ++mi)
#pragma unroll
        for (int nl = 0; nl < 2; ++nl) acc2[mi][nl] = floatx4{0.f, 0.f, 0.f, 0.f};
#pragma unroll
    for (int ks = 0; ks < 4; ++ks) {
        short8 ahi2[2], alo2[2], bhi[2], blo[2];
#pragma unroll
        for (int mi = 0; mi < 2; ++mi) {
            int row = mi * 16 + l15;
            int c5 = ks * 8 + quad * 2;
            unsigned w[8];
            *(uint4*)&w[0] = *(const uint4*)&sbuf[row * 128 + ((c5 ^ (row & 31)) * 4)];
            *(uint4*)&w[4] = *(const uint4*)&sbuf[row * 128 + (((c5 + 1) ^ (row & 31)) * 4)];
#pragma unroll
            for (int j = 0; j < 8; ++j) {
                ahi2[mi][j] = (short)(w[j] >> 16);
                alo2[mi][j] = (short)(w[j] & 0xffffu);
            }
        }
#pragma unroll
        for (int nl = 0; nl < 2; ++nl) {
            size_t p = (size_t)((wave * 2 + nl) * 16 + l15) * DIM + ks * 32 + quad * 8;
            bhi[nl] = *(const short8*)&W2hi[p];
            blo[nl] = *(const short8*)&W2lo[p];
        }
#pragma unroll
        for (int mi = 0; mi < 2; ++mi)
#pragma unroll
            for (int nl = 0; nl < 2; ++nl) {
                acc2[mi][nl] = __builtin_amdgcn_mfma_f32_16x16x32_bf16(ahi2[mi], bhi[nl], acc2[mi][nl], 0, 0, 0);
                acc2[mi][nl] = __builtin_amdgcn_mfma_f32_16x16x32_bf16(alo2[mi], bhi[nl], acc2[mi][nl], 0, 0, 0);
                acc2[mi][nl] = __builtin_amdgcn_mfma_f32_16x16x32_bf16(ahi2[mi], blo[nl], acc2[mi][nl], 0, 0, 0);
            }
    }
    __syncthreads();  // phase-3 sbuf reads done; reuse LDS for pool/stats

    // ---- phase 4: epilogue — bf16 h2 store + stats + pool (unique-writer LDS) ----
    float* pool_s = (float*)sbuf;      // [3 slot][128 col]
    float* ssum = (float*)sbuf + 384;  // [128]
    float* ssq = (float*)sbuf + 512;   // [128]

    const int g0 = batch[base];
    int idxr[2][4];
#pragma unroll
    for (int mi = 0; mi < 2; ++mi)
#pragma unroll
        for (int reg = 0; reg < 4; ++reg) {
            int row = base + mi * 16 + quad * 4 + reg;
            idxr[mi][reg] = (row < N_NODES) ? (batch[row] - g0) : -1;
        }

#pragma unroll
    for (int nl = 0; nl < 2; ++nl) {
        int col = (wave * 2 + nl) * 16 + l15;
        float bv = b2[col];
        float s_p = 0.f, q_p = 0.f, p0 = 0.f, p1 = 0.f, p2 = 0.f;
#pragma unroll
        for (int mi = 0; mi < 2; ++mi)
#pragma unroll
            for (int reg = 0; reg < 4; ++reg) {
                int idx = idxr[mi][reg];
                if (idx >= 0) {
                    int row = base + mi * 16 + quad * 4 + reg;
                    float v = fmaxf(acc2[mi][nl][reg] + bv, 0.f);
                    out[(size_t)row * DIM + col] = f2bf(v);
                    s_p += v;
                    q_p += v * v;
                    if (idx == 0) p0 += v;
                    else if (idx == 1) p1 += v;
                    else if (idx == 2) p2 += v;
                    else atomicAdd(&gout[(size_t)(g0 + idx) * OUT_STRIDE + layer * DIM + col], v);
                }
            }
        s_p += __shfl_xor(s_p, 16);
        s_p += __shfl_xor(s_p, 32);
        q_p += __shfl_xor(q_p, 16);
        q_p += __shfl_xor(q_p, 32);
        p0 += __shfl_xor(p0, 16);
        p0 += __shfl_xor(p0, 32);
        p1 += __shfl_xor(p1, 16);
        p1 += __shfl_xor(p1, 32);
        p2 += __shfl_xor(p2, 16);
        p2 += __shfl_xor(p2, 32);
        if (quad == 0) {  // unique writer per col
            ssum[col] = s_p;
            ssq[col] = q_p;
            pool_s[col] = p0;
            pool_s[128 + col] = p1;
            pool_s[256 + col] = p2;
        }
    }
    __syncthreads();

    // stats -> replicated buffer (blockIdx&15): ~98-way contention instead of 1563-way
    float* srep_b = srep + (blockIdx.x & (N_REP - 1)) * 256;
    if (tid < 128)
        atomicAdd(&srep_b[tid], ssum[tid]);
    else
        atomicAdd(&srep_b[tid], ssq[tid - 128]);
    for (int i = tid; i < 384; i += 256) {
        int slot = i >> 7, col = i & 127;
        float pv = pool_s[slot * 128 + col];
        int g = g0 + slot;
        if (pv != 0.f && g < N_GRAPHS)
            atomicAdd(&gout[(size_t)g * OUT_STRIDE + layer * DIM + col], pv);
    }
}

// ------- finalize: reduce replicas, out[b, l*128+c] = G_l[c]*rawpool + cnt[b]*OFF_l[c] -------
__global__ __launch_bounds__(384) void finalize_kernel(const float* __restrict__ rep,
                                                       const float* __restrict__ gammas,
                                                       const float* __restrict__ betas,
                                                       const int* __restrict__ cnt,
                                                       float* __restrict__ out) {
    int b = blockIdx.x;
    int t = threadIdx.x;
    int l = t >> 7, c = t & 127;
    const float* rl = rep + (size_t)l * N_REP * 256;
    float s = 0.f, q = 0.f;
#pragma unroll
    for (int r = 0; r < N_REP; ++r) {
        s += rl[r * 256 + c];
        q += rl[r * 256 + 128 + c];
    }
    const float invn = 1.0f / (float)N_NODES;
    float m = s * invn;
    float var = q * invn - m * m;
    float G = gammas[l * DIM + c] * rsqrtf(var + BN_EPS);
    float OFF = betas[l * DIM + c] - m * G;
    size_t o = (size_t)b * OUT_STRIDE + t;
    out[o] = fmaf(G, out[o], (float)cnt[b] * OFF);
}

extern "C" void kernel_launch(void* const* d_in, const int* in_sizes, int n_in,
                              void* d_out, int out_size, void* d_ws, size_t ws_size,
                              hipStream_t stream) {
    const float* x = (const float*)d_in[0];
    const int* ei = (const int*)d_in[1];
    const int* srcp = ei;
    const int* dstp = ei + N_EDGES;
    const int* batch = (const int*)d_in[2];
    const float* W1s = (const float*)d_in[3];
    const float* b1s = (const float*)d_in[4];
    const float* W2s = (const float*)d_in[5];
    const float* b2s = (const float*)d_in[6];
    const float* gammas = (const float*)d_in[7];
    const float* betas = (const float*)d_in[8];
    float* out = (float*)d_out;

    const size_t NF = (size_t)N_NODES * DIM;  // 6.4M elements
    short* hbufA = (short*)d_ws;              // bf16 [N,128]
    short* hbufB = hbufA + NF;                // bf16 [N,128]
    short* xb = hbufB + NF;                   // bf16 [N,128] (x converted)
    short* whi = xb + NF;                     // bf16 hi [6][128][128]
    short* wlo = whi + 6 * DIM * DIM;         // bf16 lo [6][128][128]
    float* stats_rep = (float*)(wlo + 6 * DIM * DIM);  // [3][N_REP][256]
    int* cnt = (int*)(stats_rep + 3 * N_REP * 256);    // 512
    int* deg = cnt + N_GRAPHS;                // 50000
    unsigned short* esrc = (unsigned short*)(deg + N_NODES);  // buckets [N][CAP] ushort (6.4 MB)

    hipMemsetAsync(out, 0, (size_t)N_GRAPHS * OUT_STRIDE * sizeof(float), stream);
    // zero stats_rep + cnt + deg (contiguous)
    hipMemsetAsync(stats_rep, 0,
                   (3 * N_REP * 256) * sizeof(float) + (N_GRAPHS + N_NODES) * sizeof(int), stream);

    // one prep dispatch: bucket-CSR + counts + weight/x converts
    prep_kernel<<<(N_NODES * 32 + 255) / 256, 256, 0, stream>>>(srcp, dstp, batch, deg, cnt, esrc,
                                                                W1s, W2s, whi, wlo, x, xb);

    const int nblk = (N_NODES + 31) / 32;  // 1563
    const short* hin = xb;
    short* hout = hbufA;
    for (int layer = 0; layer < N_LAYERS; ++layer) {
        const float* prevrep =
            (layer == 0) ? nullptr : (stats_rep + (size_t)(layer - 1) * N_REP * 256);
        fused_layer_kernel<<<nblk, 256, 0, stream>>>(
            hin, deg, esrc, prevrep, gammas + (layer - 1) * DIM, betas + (layer - 1) * DIM,
            whi + ((size_t)layer << 14), wlo + ((size_t)layer << 14), b1s + layer * DIM,
            whi + ((size_t)(3 + layer) << 14), wlo + ((size_t)(3 + layer) << 14),
            b2s + layer * DIM, batch, hout, stats_rep + (size_t)layer * N_REP * 256, out, layer);
        hin = hout;
        hout = (hout == hbufA) ? hbufB : hbufA;
    }
    finalize_kernel<<<N_GRAPHS, 384, 0, stream>>>(stats_rep, gammas, betas, cnt, out);
}